// Round 4
// baseline (221.481 us; speedup 1.0000x reference)
//
#include <hip/hip_runtime.h>
#include <hip/hip_bf16.h>

// Problem constants (from reference setup_inputs): B,H,T,D fixed.
constexpr int B = 2, H = 16, T = 2048, D = 64;
constexpr int NS = T / 16;                   // 128 strided key positions
constexpr int WAVES = 4, BLOCK = 256;        // 4 waves per block
constexpr int CHUNKS = 16;                   // q-row chunks per (b,h)
constexpr int ROWS_PER_BLOCK = T / CHUNKS;   // 128
constexpr int ROWS_PER_WAVE = ROWS_PER_BLOCK / WAVES; // 32
constexpr int R = 4;                         // rows per group (amortize K sweeps)
constexpr int GROUPS = ROWS_PER_WAVE / R;    // 8

// One wave owns 32 q-rows, in groups of 4. Per group:
//  - scores: lane l owns keys j=l, j=l+64; Ks XOR-swizzled b128 (conflict-free),
//    q via LDS broadcast; 4 rows share each Ks sweep.
//  - per-row diag score + wave softmax (masked -> exp underflow = exact 0).
//  - PV: lane = (jq=lane>>4, dq=lane&15). Lane owns d-quad [4dq,4dq+4) and the
//    j's {4*jj+jq}; V read DIRECTLY FROM GLOBAL as b128 (VMEM pipe, L2-hot,
//    keeps the LDS pipe free); p broadcast hits 4 distinct banks; partials
//    reduced with shfl_xor(16|32); diag V row added as a multicast b128.
//  - streams 4 full 8KB attn rows as coalesced float4 (each 64B line once).
// q_lds/p_lds are per-wave private: no barrier in the row loop (wave64 lockstep).
// LDS = 44.5KB -> 3 blocks/CU (12 waves) for store-issue overlap.
__global__ __launch_bounds__(BLOCK, 3)
void strided_attn_kernel(const float* __restrict__ q,
                         const float* __restrict__ k,
                         const float* __restrict__ v,
                         const int*   __restrict__ mask,
                         float* __restrict__ out,
                         float* __restrict__ attn)
{
    __shared__ float4 Ks4[NS][16];         // K[16j][4c..4c+3] at Ks4[j][c ^ (j&15)]
    __shared__ float  q_lds[WAVES][R][64]; // per-wave private
    __shared__ float  p_lds[WAVES][R][NS]; // per-wave private
    __shared__ int    msk[NS];

    const int blk   = blockIdx.x;
    const int bh    = blk / CHUNKS;
    const int chunk = blk % CHUNKS;
    const int b     = bh / H;

    const float* qb = q + (size_t)bh * T * D;
    const float* kb = k + (size_t)bh * T * D;
    const float* vb = v + (size_t)bh * T * D;
    const int*   mb = mask + (size_t)b * T;

    const int tid = threadIdx.x;

    // Stage strided K rows (swizzled float4): 16 lanes cover one 256B row.
    for (int i = tid; i < NS * 16; i += BLOCK) {
        const int j = i >> 4, c = i & 15;
        Ks4[j][c ^ (j & 15)] =
            *reinterpret_cast<const float4*>(kb + (size_t)(j * 16) * D + c * 4);
    }
    if (tid < NS) msk[tid] = mb[tid * 16];
    __syncthreads();   // the only block-wide barrier

    const int wave = tid >> 6, lane = tid & 63;
    const int row0 = chunk * ROWS_PER_BLOCK + wave * ROWS_PER_WAVE;
    const int j0 = lane, j1 = lane + 64;
    const int xsw = lane & 15;             // same swizzle for j0/j1
    const int m0 = msk[j0], m1 = msk[j1];
    const int dq = lane & 15, jq = lane >> 4;   // PV decomposition

    for (int g = 0; g < GROUPS; ++g) {
        const int grow = row0 + g * R;     // 4 consecutive q-rows

        // Stage q for 4 rows: 256 contiguous floats, one b128 per lane.
        *reinterpret_cast<float4*>(&q_lds[wave][0][0] + lane * 4) =
            *reinterpret_cast<const float4*>(qb + (size_t)grow * D + lane * 4);

        // ---- scores: 32 swizzled b128 Ks reads shared across 4 rows ----
        float s0[R] = {0.f, 0.f, 0.f, 0.f};
        float s1[R] = {0.f, 0.f, 0.f, 0.f};
        #pragma unroll
        for (int c = 0; c < 16; ++c) {
            const float4 k0 = Ks4[j0][c ^ xsw];
            const float4 k1 = Ks4[j1][c ^ xsw];
            #pragma unroll
            for (int r = 0; r < R; ++r) {
                const float4 q4 = *reinterpret_cast<const float4*>(&q_lds[wave][r][c * 4]);
                s0[r] = fmaf(q4.w, k0.w, fmaf(q4.z, k0.z, fmaf(q4.y, k0.y, fmaf(q4.x, k0.x, s0[r]))));
                s1[r] = fmaf(q4.w, k1.w, fmaf(q4.z, k1.z, fmaf(q4.y, k1.y, fmaf(q4.x, k1.x, s1[r]))));
            }
        }

        // ---- per-row mask, diag, softmax; p -> per-wave LDS ----
        float pd[R];
        bool  qmod[R];
        #pragma unroll
        for (int r = 0; r < R; ++r) {
            const int qrow = grow + r;
            float a0 = s0[r] * 0.125f, a1 = s1[r] * 0.125f;
            if (m0 == 0) a0 = -1e9f;
            if (m1 == 0) a1 = -1e9f;

            // diag score: dot(q_row, k_row) butterfly
            float part = q_lds[wave][r][lane] * kb[(size_t)qrow * D + lane];
            #pragma unroll
            for (int s = 32; s > 0; s >>= 1) part += __shfl_xor(part, s, 64);
            float sd = part * 0.125f;
            qmod[r] = (qrow & 15) == 0;    // diag coincides with a strided slot
            if (mb[qrow] == 0) sd = -1e9f;

            float m = fmaxf(a0, a1);
            #pragma unroll
            for (int s = 32; s > 0; s >>= 1) m = fmaxf(m, __shfl_xor(m, s, 64));
            if (!qmod[r]) m = fmaxf(m, sd);

            const float e0 = __expf(a0 - m);   // masked -> exact 0 (underflow)
            const float e1 = __expf(a1 - m);
            const float ed = qmod[r] ? 0.f : __expf(sd - m);
            float sum = e0 + e1;
            #pragma unroll
            for (int s = 32; s > 0; s >>= 1) sum += __shfl_xor(sum, s, 64);
            sum += ed;
            const float inv = 1.f / sum;

            p_lds[wave][r][j0] = e0 * inv;
            p_lds[wave][r][j1] = e1 * inv;
            pd[r] = ed * inv;
        }

        // ---- PV: lane=(jq,dq); V from GLOBAL b128; p multicast (4 banks) ----
        float4 acc[R];
        #pragma unroll
        for (int r = 0; r < R; ++r) acc[r] = make_float4(0.f, 0.f, 0.f, 0.f);

        #pragma unroll 8
        for (int jj = 0; jj < 32; ++jj) {
            const int j = jj * 4 + jq;     // j%4==jq -> p banks distinct
            const float4 v4 =
                *reinterpret_cast<const float4*>(vb + (size_t)(j * 16) * D + dq * 4);
            #pragma unroll
            for (int r = 0; r < R; ++r) {
                const float pj = p_lds[wave][r][j];
                acc[r].x = fmaf(pj, v4.x, acc[r].x);
                acc[r].y = fmaf(pj, v4.y, acc[r].y);
                acc[r].z = fmaf(pj, v4.z, acc[r].z);
                acc[r].w = fmaf(pj, v4.w, acc[r].w);
            }
        }
        // reduce over the 4 j-quarters (lane bits 4,5)
        #pragma unroll
        for (int r = 0; r < R; ++r) {
            acc[r].x += __shfl_xor(acc[r].x, 16, 64);
            acc[r].y += __shfl_xor(acc[r].y, 16, 64);
            acc[r].z += __shfl_xor(acc[r].z, 16, 64);
            acc[r].w += __shfl_xor(acc[r].w, 16, 64);
            acc[r].x += __shfl_xor(acc[r].x, 32, 64);
            acc[r].y += __shfl_xor(acc[r].y, 32, 64);
            acc[r].z += __shfl_xor(acc[r].z, 32, 64);
            acc[r].w += __shfl_xor(acc[r].w, 32, 64);
        }

        // ---- diag V add + out store (16 lanes, 256B coalesced) ----
        #pragma unroll
        for (int r = 0; r < R; ++r) {
            const int qrow = grow + r;
            const float4 vd =
                *reinterpret_cast<const float4*>(vb + (size_t)qrow * D + dq * 4);
            acc[r].x = fmaf(pd[r], vd.x, acc[r].x);
            acc[r].y = fmaf(pd[r], vd.y, acc[r].y);
            acc[r].z = fmaf(pd[r], vd.z, acc[r].z);
            acc[r].w = fmaf(pd[r], vd.w, acc[r].w);
            if (jq == 0)
                *reinterpret_cast<float4*>(out + ((size_t)bh * T + qrow) * D + dq * 4) = acc[r];
        }

        // ---- attn streaming stores (coalesced float4, each line once) ----
        #pragma unroll
        for (int r = 0; r < R; ++r) {
            const int qrow = grow + r;
            float4* arow = reinterpret_cast<float4*>(attn + ((size_t)bh * T + qrow) * (size_t)T);
            const int fq = qrow >> 2;      // float4 index containing the diagonal
            const int dc = qrow & 3;
            #pragma unroll
            for (int t = 0; t < 8; ++t) {
                const int f = t * 64 + lane;
                float4 val = make_float4(0.f, 0.f, 0.f, 0.f);
                if ((f & 3) == 0) val.x = p_lds[wave][r][f >> 2];   // k = 16*(f>>2)
                if (!qmod[r] && f == fq) {
                    if      (dc == 0) val.x = pd[r];
                    else if (dc == 1) val.y = pd[r];
                    else if (dc == 2) val.z = pd[r];
                    else              val.w = pd[r];
                }
                arow[f] = val;
            }
        }
    }
}

extern "C" void kernel_launch(void* const* d_in, const int* in_sizes, int n_in,
                              void* d_out, int out_size, void* d_ws, size_t ws_size,
                              hipStream_t stream) {
    const float* q    = (const float*)d_in[0];
    const float* k    = (const float*)d_in[1];
    const float* v    = (const float*)d_in[2];
    const int*   mask = (const int*)d_in[3];

    float* out  = (float*)d_out;
    float* attn = out + (size_t)B * H * T * D;   // tuple outputs concatenated flat

    dim3 grid(B * H * CHUNKS);   // 512 blocks; 44.5KB LDS -> 3/CU, 12 waves/CU
    dim3 block(BLOCK);
    hipLaunchKernelGGL(strided_attn_kernel, grid, block, 0, stream,
                       q, k, v, mask, out, attn);
}

// Round 5
// 177.680 us; speedup vs baseline: 1.2465x; 1.2465x over previous
//
#include <hip/hip_runtime.h>
#include <hip/hip_bf16.h>

// Problem constants (from reference setup_inputs): B,H,T,D fixed.
constexpr int B = 2, H = 16, T = 2048, D = 64;
constexpr int NS = T / 16;                   // 128 strided key positions
constexpr int WAVES = 4, BLOCK = 256;        // 4 waves per block
constexpr int CHUNKS = 16;                   // q-row chunks per (b,h)
constexpr int ROWS_PER_BLOCK = T / CHUNKS;   // 128
constexpr int ROWS_PER_WAVE = ROWS_PER_BLOCK / WAVES; // 32
constexpr int R = 4;                         // rows per group (amortize K/V sweeps)
constexpr int GROUPS = ROWS_PER_WAVE / R;    // 8

// Uniform-index lane broadcast: v_readlane -> SGPR (VALU/SALU, zero LDS-pipe).
__device__ __forceinline__ float rlf(float v, int l) {
    return __int_as_float(__builtin_amdgcn_readlane(__float_as_int(v), l));
}

// R2 structure (best: 167us) with all LDS *broadcasts* moved to v_readlane:
//  - scores: lane l owns keys j=l, j=l+64; Ks XOR-swizzled b128 (conflict-free);
//    q held as one float4/lane register, q[r][c] broadcast via readlane
//    (replaces 768 cyc/group of LDS q4 broadcasts).
//  - softmax per row; p kept in registers p0[r]/p1[r]; PV broadcasts them via
//    readlane (replaces 1536 cyc/group of LDS p4 broadcasts). p_lds written
//    only for the attn-store gather (8 b32/row).
//  - PV: lane = d; Vs b32 reads (bank = lane%32, 2-way = free) shared over 4 rows.
//  - V stays in LDS (R4 showed global-V latency is NOT hidden at 2 waves/SIMD).
//  - streams 4 full 8KB attn rows as coalesced float4 (each 64B line once).
// q_lds removed entirely. No barrier in the row loop (per-wave-private state).
__global__ __launch_bounds__(BLOCK, 2)
void strided_attn_kernel(const float* __restrict__ q,
                         const float* __restrict__ k,
                         const float* __restrict__ v,
                         const int*   __restrict__ mask,
                         float* __restrict__ out,
                         float* __restrict__ attn)
{
    __shared__ float4 Ks4[NS][16];         // K[16j][4c..4c+3] at Ks4[j][c ^ (j&15)]
    __shared__ float  Vs[NS * 64];         // row-major; b32 reads conflict-free (lane=d)
    __shared__ float  p_lds[WAVES][R][NS]; // per-wave private (attn-store gather only)
    __shared__ int    msk[NS];

    const int blk   = blockIdx.x;
    const int bh    = blk / CHUNKS;
    const int chunk = blk % CHUNKS;
    const int b     = bh / H;

    const float* qb = q + (size_t)bh * T * D;
    const float* kb = k + (size_t)bh * T * D;
    const float* vb = v + (size_t)bh * T * D;
    const int*   mb = mask + (size_t)b * T;

    const int tid = threadIdx.x;

    // Stage strided K (swizzled float4) and V (row-major). 16 lanes per 256B row.
    for (int i = tid; i < NS * 16; i += BLOCK) {
        const int j = i >> 4, c = i & 15;
        Ks4[j][c ^ (j & 15)] =
            *reinterpret_cast<const float4*>(kb + (size_t)(j * 16) * D + c * 4);
        *reinterpret_cast<float4*>(Vs + j * 64 + c * 4) =
            *reinterpret_cast<const float4*>(vb + (size_t)(j * 16) * D + c * 4);
    }
    if (tid < NS) msk[tid] = mb[tid * 16];
    __syncthreads();   // the only block-wide barrier

    const int wave = tid >> 6, lane = tid & 63;
    const int row0 = chunk * ROWS_PER_BLOCK + wave * ROWS_PER_WAVE;
    const int j0 = lane, j1 = lane + 64;
    const int xsw = lane & 15;             // same swizzle for j0/j1
    const int m0 = msk[j0], m1 = msk[j1];

    for (int g = 0; g < GROUPS; ++g) {
        const int grow = row0 + g * R;     // 4 consecutive q-rows

        // q for 4 rows in registers: lane holds q[grow + lane/16][4*(lane%16)..+3]
        const float4 qv =
            *reinterpret_cast<const float4*>(qb + (size_t)grow * D + lane * 4);

        // ---- scores: 32 swizzled b128 Ks reads; q broadcast via readlane ----
        float s0[R] = {0.f, 0.f, 0.f, 0.f};
        float s1[R] = {0.f, 0.f, 0.f, 0.f};
        #pragma unroll
        for (int cq = 0; cq < 16; ++cq) {
            const float4 k0 = Ks4[j0][cq ^ xsw];
            const float4 k1 = Ks4[j1][cq ^ xsw];
            #pragma unroll
            for (int r = 0; r < R; ++r) {
                const int src = 16 * r + cq;          // lane holding q[r][4cq..4cq+3]
                const float qx = rlf(qv.x, src);
                const float qy = rlf(qv.y, src);
                const float qz = rlf(qv.z, src);
                const float qw = rlf(qv.w, src);
                s0[r] = fmaf(qw, k0.w, fmaf(qz, k0.z, fmaf(qy, k0.y, fmaf(qx, k0.x, s0[r]))));
                s1[r] = fmaf(qw, k1.w, fmaf(qz, k1.z, fmaf(qy, k1.y, fmaf(qx, k1.x, s1[r]))));
            }
        }

        // ---- per-row mask, diag, softmax; p kept in REGISTERS ----
        float p0[R], p1[R], pd[R];
        bool  qmod[R];
        #pragma unroll
        for (int r = 0; r < R; ++r) {
            const int qrow = grow + r;
            float a0 = s0[r] * 0.125f, a1 = s1[r] * 0.125f;
            if (m0 == 0) a0 = -1e9f;
            if (m1 == 0) a1 = -1e9f;

            // diag score: per-lane q,k from global (b32 coalesced, L1/L2-hot)
            float part = qb[(size_t)qrow * D + lane] * kb[(size_t)qrow * D + lane];
            #pragma unroll
            for (int s = 32; s > 0; s >>= 1) part += __shfl_xor(part, s, 64);
            float sd = part * 0.125f;
            qmod[r] = (qrow & 15) == 0;    // diag coincides with a strided slot
            if (mb[qrow] == 0) sd = -1e9f;

            float m = fmaxf(a0, a1);
            #pragma unroll
            for (int s = 32; s > 0; s >>= 1) m = fmaxf(m, __shfl_xor(m, s, 64));
            if (!qmod[r]) m = fmaxf(m, sd);

            const float e0 = __expf(a0 - m);   // masked -> exact 0 (underflow)
            const float e1 = __expf(a1 - m);
            const float ed = qmod[r] ? 0.f : __expf(sd - m);
            float sum = e0 + e1;
            #pragma unroll
            for (int s = 32; s > 0; s >>= 1) sum += __shfl_xor(sum, s, 64);
            sum += ed;
            const float inv = 1.f / sum;

            p0[r] = e0 * inv;
            p1[r] = e1 * inv;
            pd[r] = ed * inv;
            p_lds[wave][r][j0] = p0[r];        // for attn-store gather only
            p_lds[wave][r][j1] = p1[r];
        }

        // ---- PV: lane = d; Vs b32 shared over rows; p broadcast via readlane ----
        float acc[R];
        #pragma unroll
        for (int r = 0; r < R; ++r)
            acc[r] = pd[r] * vb[(size_t)(grow + r) * D + lane];

        #pragma unroll 16
        for (int j = 0; j < 64; ++j) {
            const float vj = Vs[j * 64 + lane];
            #pragma unroll
            for (int r = 0; r < R; ++r)
                acc[r] = fmaf(rlf(p0[r], j), vj, acc[r]);
        }
        #pragma unroll 16
        for (int j = 0; j < 64; ++j) {
            const float vj = Vs[(j + 64) * 64 + lane];
            #pragma unroll
            for (int r = 0; r < R; ++r)
                acc[r] = fmaf(rlf(p1[r], j), vj, acc[r]);
        }

        // ---- out stores (lane = d, 256B coalesced) ----
        #pragma unroll
        for (int r = 0; r < R; ++r)
            out[((size_t)bh * T + grow + r) * D + lane] = acc[r];

        // ---- attn streaming stores (coalesced float4, each line once) ----
        #pragma unroll
        for (int r = 0; r < R; ++r) {
            const int qrow = grow + r;
            float4* arow = reinterpret_cast<float4*>(attn + ((size_t)bh * T + qrow) * (size_t)T);
            const int fq = qrow >> 2;      // float4 index containing the diagonal
            const int dc = qrow & 3;
            #pragma unroll
            for (int t = 0; t < 8; ++t) {
                const int f = t * 64 + lane;
                float4 val = make_float4(0.f, 0.f, 0.f, 0.f);
                if ((f & 3) == 0) val.x = p_lds[wave][r][f >> 2];   // k = 16*(f>>2)
                if (!qmod[r] && f == fq) {
                    if      (dc == 0) val.x = pd[r];
                    else if (dc == 1) val.y = pd[r];
                    else if (dc == 2) val.z = pd[r];
                    else              val.w = pd[r];
                }
                arow[f] = val;
            }
        }
    }
}

extern "C" void kernel_launch(void* const* d_in, const int* in_sizes, int n_in,
                              void* d_out, int out_size, void* d_ws, size_t ws_size,
                              hipStream_t stream) {
    const float* q    = (const float*)d_in[0];
    const float* k    = (const float*)d_in[1];
    const float* v    = (const float*)d_in[2];
    const int*   mask = (const int*)d_in[3];

    float* out  = (float*)d_out;
    float* attn = out + (size_t)B * H * T * D;   // tuple outputs concatenated flat

    dim3 grid(B * H * CHUNKS);   // 512 blocks = 2/CU (72.5KB LDS also caps at 2)
    dim3 block(BLOCK);
    hipLaunchKernelGGL(strided_attn_kernel, grid, block, 0, stream,
                       q, k, v, mask, out, attn);
}